// Round 5
// baseline (1209.561 us; speedup 1.0000x reference)
//
#include <hip/hip_runtime.h>
#include <stdint.h>

#define N_ROWS 8192
#define D_DIM  1024   // bytes per row in fp8

typedef __attribute__((ext_vector_type(8)))  int   i32x8;
typedef __attribute__((ext_vector_type(4)))  int   i32x4;
typedef __attribute__((ext_vector_type(4)))  float f32x4;

#define GLD16(gptr, lptr) __builtin_amdgcn_global_load_lds( \
    (const __attribute__((address_space(1))) void*)(gptr),  \
    (__attribute__((address_space(3))) void*)(lptr), 16, 0, 0)

// fp32 -> fp8 e4m3. img scaled by 4*logit_scale, txt by 64 -> acc = 256*logit.
// Tail blocks zero-init row_sum/col_sum/dsum/counter.
__global__ void convert_zero_kernel(const float* __restrict__ img,
                                    const float* __restrict__ txt,
                                    const float* __restrict__ scale_p,
                                    char* __restrict__ imgq, char* __restrict__ txtq,
                                    float* __restrict__ rs_base) {
    const int b = blockIdx.x;
    if (b >= 4096) {              // 64 zero-init blocks
        const int idx = (b - 4096) * 256 + threadIdx.x;
        rs_base[idx] = 0.f;       // row_sum[0..8191], col_sum[0..8191]
        if (idx < 2) ((int*)(rs_base + 2 * N_ROWS))[idx] = 0;  // dsum, counter
        return;
    }
    const bool is_img = b < 2048;
    const float f     = is_img ? scale_p[0] * 4.0f : 64.0f;
    const float* src  = is_img ? img : txt;
    char* dst         = is_img ? imgq : txtq;
    const size_t idx  = ((size_t)(is_img ? b : b - 2048) * 256 + threadIdx.x) * 16;

    float4 x0 = *(const float4*)(src + idx);
    float4 x1 = *(const float4*)(src + idx + 4);
    float4 x2 = *(const float4*)(src + idx + 8);
    float4 x3 = *(const float4*)(src + idx + 12);
    int p0 = __builtin_amdgcn_cvt_pk_fp8_f32(x0.x * f, x0.y * f, 0, false);
    p0     = __builtin_amdgcn_cvt_pk_fp8_f32(x0.z * f, x0.w * f, p0, true);
    int p1 = __builtin_amdgcn_cvt_pk_fp8_f32(x1.x * f, x1.y * f, 0, false);
    p1     = __builtin_amdgcn_cvt_pk_fp8_f32(x1.z * f, x1.w * f, p1, true);
    int p2 = __builtin_amdgcn_cvt_pk_fp8_f32(x2.x * f, x2.y * f, 0, false);
    p2     = __builtin_amdgcn_cvt_pk_fp8_f32(x2.z * f, x2.w * f, p2, true);
    int p3 = __builtin_amdgcn_cvt_pk_fp8_f32(x3.x * f, x3.y * f, 0, false);
    p3     = __builtin_amdgcn_cvt_pk_fp8_f32(x3.z * f, x3.w * f, p3, true);
    *(i32x4*)(dst + idx) = (i32x4){p0, p1, p2, p3};
}

// 128x128 tile, MX-fp8 K=128 MFMA (unit scales), R1/R4's exact 4x4 quad/l15
// fragment structure + XOR swizzle (the 0-conflict layout). Epilogue: diag sum
// (diag blocks), exp2, row/col atomics, last-block ticket finish.
__global__ void gemm_exp_kernel(const char* __restrict__ A,   // img fp8, x4*scale
                                const char* __restrict__ B,   // txt fp8, x64
                                float* __restrict__ row_sum,
                                float* __restrict__ col_sum,
                                float* __restrict__ dsum,     // sum of true diag logits
                                int*   __restrict__ counter,
                                float* __restrict__ out) {
    __shared__ __align__(16) char As[128 * 128];
    __shared__ __align__(16) char Bs[128 * 128];

    const int tid  = threadIdx.x;
    const int lane = tid & 63;
    const int w    = tid >> 6;      // wave 0..3
    const int wr   = w >> 1;
    const int wc   = w & 1;
    const int ti   = blockIdx.y * 128;
    const int tj   = blockIdx.x * 128;

    const int quad = lane >> 4;
    const int l15  = lane & 15;

    const int srow = lane >> 3;               // 0..7
    const int sg   = (lane & 7) ^ srow;       // XOR-swizzled 16B k-chunk

    f32x4 acc[4][4];
#pragma unroll
    for (int i = 0; i < 4; i++)
#pragma unroll
        for (int j = 0; j < 4; j++) acc[i][j] = (f32x4){0.f, 0.f, 0.f, 0.f};

    const int arow = wr * 64 + l15;
    const int brow = wc * 64 + l15;

    for (int k0 = 0; k0 < D_DIM; k0 += 128) {
#pragma unroll
        for (int c = 0; c < 4; c++) {
            const int ch = w * 4 + c;             // wave-uniform
            const int r  = ch * 8 + srow;         // tile row 0..127
            GLD16(A + (size_t)(ti + r) * D_DIM + k0 + sg * 16, As + ch * 1024);
            GLD16(B + (size_t)(tj + r) * D_DIM + k0 + sg * 16, Bs + ch * 1024);
        }
        __syncthreads();
        i32x8 af[4], bfb[4];
#pragma unroll
        for (int fr = 0; fr < 4; fr++) {
            const int row = arow + fr * 16;
            const char* base = As + row * 128;
            const int p0 = (((quad << 1) ^ (row & 7)) << 4);  // lane's k = quad*32..+31
            i32x4 lo = *(const i32x4*)(base + p0);
            i32x4 hi = *(const i32x4*)(base + (p0 ^ 16));
            af[fr] = (i32x8){lo.x, lo.y, lo.z, lo.w, hi.x, hi.y, hi.z, hi.w};
        }
#pragma unroll
        for (int fc = 0; fc < 4; fc++) {
            const int row = brow + fc * 16;
            const char* base = Bs + row * 128;
            const int p0 = (((quad << 1) ^ (row & 7)) << 4);
            i32x4 lo = *(const i32x4*)(base + p0);
            i32x4 hi = *(const i32x4*)(base + (p0 ^ 16));
            bfb[fc] = (i32x8){lo.x, lo.y, lo.z, lo.w, hi.x, hi.y, hi.z, hi.w};
        }
#pragma unroll
        for (int fr = 0; fr < 4; fr++)
#pragma unroll
            for (int fc = 0; fc < 4; fc++)
                acc[fr][fc] = __builtin_amdgcn_mfma_scale_f32_16x16x128_f8f6f4(
                    af[fr], bfb[fc], acc[fr][fc], 0, 0, 0, 127, 0, 127);
        __syncthreads();
    }

    // ---- diag: acc = 256 * logit ----
    if (blockIdx.x == blockIdx.y && wr == wc) {
        float dloc = 0.f;
#pragma unroll
        for (int fr = 0; fr < 4; fr++)
#pragma unroll
            for (int r = 0; r < 4; r++)
                if (l15 == quad * 4 + r) dloc += acc[fr][fr][r];
#pragma unroll
        for (int m = 1; m < 64; m <<= 1) dloc += __shfl_xor(dloc, m);
        if (lane == 0) atomicAdd(dsum, dloc * (1.0f / 256.0f));
    }

    // ---- exp: exp(logit) = exp2(acc * log2e/256) ----
    const float C_EXP = 1.44269504088896340736f / 256.0f;
#pragma unroll
    for (int fr = 0; fr < 4; fr++)
#pragma unroll
        for (int fc = 0; fc < 4; fc++)
#pragma unroll
            for (int r = 0; r < 4; r++)
                acc[fr][fc][r] = __builtin_amdgcn_exp2f(acc[fr][fc][r] * C_EXP);

    // row sums: elem (fr,fc,r) = exp(l[ti+wr*64+fr*16+quad*4+r][tj+wc*64+fc*16+l15])
    const int rowbase = ti + wr * 64;
#pragma unroll
    for (int fr = 0; fr < 4; fr++) {
#pragma unroll
        for (int r = 0; r < 4; r++) {
            float s = acc[fr][0][r] + acc[fr][1][r] + acc[fr][2][r] + acc[fr][3][r];
            s += __shfl_xor(s, 1);
            s += __shfl_xor(s, 2);
            s += __shfl_xor(s, 4);
            s += __shfl_xor(s, 8);
            if (l15 == 0)
                atomicAdd(&row_sum[rowbase + fr * 16 + quad * 4 + r], s);
        }
    }

    // col sums
    const int colbase = tj + wc * 64;
#pragma unroll
    for (int fc = 0; fc < 4; fc++) {
        float s = 0.f;
#pragma unroll
        for (int fr = 0; fr < 4; fr++)
#pragma unroll
            for (int r = 0; r < 4; r++) s += acc[fr][fc][r];
        s += __shfl_xor(s, 16);
        s += __shfl_xor(s, 32);
        if (quad == 0)
            atomicAdd(&col_sum[colbase + fc * 16 + l15], s);
    }

    // ---- last-block finish ----
    // Workgroup release = s_waitcnt vmcnt(0) only (no L2 maintenance — R3 lesson);
    // device-scope atomics carry the data to the coherence point.
    __builtin_amdgcn_fence(__ATOMIC_RELEASE, "workgroup");
    int*   sh_flag = (int*)Bs;    // LDS reuse, keep LDS_Block_Size = 32768
    float* sh_sum  = (float*)As;
    if (tid == 0) sh_flag[0] = (atomicAdd(counter, 1) == (64 * 64 - 1)) ? 1 : 0;
    __syncthreads();
    if (sh_flag[0]) {
        // ONE agent-scope acquire (single buffer_inv in a single block): makes
        // plain coalesced loads below see all device-scope atomic results.
        __builtin_amdgcn_fence(__ATOMIC_ACQUIRE, "agent");
        float s = 0.f;
        for (int i = tid * 4; i < N_ROWS; i += 1024) {   // 8 iters, float4 loads
            float4 r = *(const float4*)(row_sum + i);
            float4 c = *(const float4*)(col_sum + i);
            s += __logf(r.x * r.y * r.z * r.w) + __logf(c.x * c.y * c.z * c.w);
        }
#pragma unroll
        for (int m = 1; m < 64; m <<= 1) s += __shfl_xor(s, m);
        if (lane == 0) sh_sum[w] = s;
        __syncthreads();
        if (tid == 0) {
            float t = sh_sum[0] + sh_sum[1] + sh_sum[2] + sh_sum[3];
            out[0] = (t - 2.0f * dsum[0]) * (0.5f / (float)N_ROWS);
        }
    }
}

extern "C" void kernel_launch(void* const* d_in, const int* in_sizes, int n_in,
                              void* d_out, int out_size, void* d_ws, size_t ws_size,
                              hipStream_t stream) {
    const float* img     = (const float*)d_in[0];
    const float* txt     = (const float*)d_in[1];
    const float* scale_p = (const float*)d_in[2];
    float* out = (float*)d_out;

    char* ws = (char*)d_ws;
    char*  imgq    = ws;                                          // 8 MB
    char*  txtq    = ws + (size_t)8 * 1024 * 1024;                // 8 MB
    float* row_sum = (float*)(ws + (size_t)16 * 1024 * 1024);     // 32 KB
    float* col_sum = row_sum + N_ROWS;                            // 32 KB
    float* dsum    = row_sum + 2 * N_ROWS;
    int*   counter = (int*)(row_sum + 2 * N_ROWS) + 1;

    convert_zero_kernel<<<4096 + 64, 256, 0, stream>>>(img, txt, scale_p,
                                                       imgq, txtq, row_sum);

    dim3 grid(N_ROWS / 128, N_ROWS / 128);
    gemm_exp_kernel<<<grid, 256, 0, stream>>>(imgq, txtq, row_sum, col_sum,
                                              dsum, counter, out);
}

// Round 6
// 1030.088 us; speedup vs baseline: 1.1742x; 1.1742x over previous
//
#include <hip/hip_runtime.h>
#include <stdint.h>

#define N_ROWS 8192
#define D_DIM  1024   // bytes per row in fp8

typedef __attribute__((ext_vector_type(8)))  int   i32x8;
typedef __attribute__((ext_vector_type(4)))  int   i32x4;
typedef __attribute__((ext_vector_type(4)))  float f32x4;

#define GLD16(gptr, lptr) __builtin_amdgcn_global_load_lds( \
    (const __attribute__((address_space(1))) void*)(gptr),  \
    (__attribute__((address_space(3))) void*)(lptr), 16, 0, 0)

// fp32 -> fp8 e4m3. img scaled by 4*logit_scale, txt by 64 -> acc = 256*logit.
// Tail blocks zero-init row_sum/col_sum/dsum/counter.
__global__ void convert_zero_kernel(const float* __restrict__ img,
                                    const float* __restrict__ txt,
                                    const float* __restrict__ scale_p,
                                    char* __restrict__ imgq, char* __restrict__ txtq,
                                    float* __restrict__ rs_base) {
    const int b = blockIdx.x;
    if (b >= 4096) {              // 64 zero-init blocks
        const int idx = (b - 4096) * 256 + threadIdx.x;
        rs_base[idx] = 0.f;       // row_sum[0..8191], col_sum[0..8191]
        if (idx < 2) ((int*)(rs_base + 2 * N_ROWS))[idx] = 0;  // dsum, counter
        return;
    }
    const bool is_img = b < 2048;
    const float f     = is_img ? scale_p[0] * 4.0f : 64.0f;
    const float* src  = is_img ? img : txt;
    char* dst         = is_img ? imgq : txtq;
    const size_t idx  = ((size_t)(is_img ? b : b - 2048) * 256 + threadIdx.x) * 16;

    float4 x0 = *(const float4*)(src + idx);
    float4 x1 = *(const float4*)(src + idx + 4);
    float4 x2 = *(const float4*)(src + idx + 8);
    float4 x3 = *(const float4*)(src + idx + 12);
    int p0 = __builtin_amdgcn_cvt_pk_fp8_f32(x0.x * f, x0.y * f, 0, false);
    p0     = __builtin_amdgcn_cvt_pk_fp8_f32(x0.z * f, x0.w * f, p0, true);
    int p1 = __builtin_amdgcn_cvt_pk_fp8_f32(x1.x * f, x1.y * f, 0, false);
    p1     = __builtin_amdgcn_cvt_pk_fp8_f32(x1.z * f, x1.w * f, p1, true);
    int p2 = __builtin_amdgcn_cvt_pk_fp8_f32(x2.x * f, x2.y * f, 0, false);
    p2     = __builtin_amdgcn_cvt_pk_fp8_f32(x2.z * f, x2.w * f, p2, true);
    int p3 = __builtin_amdgcn_cvt_pk_fp8_f32(x3.x * f, x3.y * f, 0, false);
    p3     = __builtin_amdgcn_cvt_pk_fp8_f32(x3.z * f, x3.w * f, p3, true);
    *(i32x4*)(dst + idx) = (i32x4){p0, p1, p2, p3};
}

// 128x128 tile, MX-fp8 K=128 (unit scales). Spill-proofed: launch_bounds
// relaxes the VGPR budget (R5 spilled 2GB of scratch at a 64-reg cap);
// 32B-chunk XOR swizzle makes each fragment ONE contiguous i32x8 LDS load;
// b-frags preloaded, a-frags streamed. Math identical to R5 (absmax 0.0).
__global__ void __launch_bounds__(256, 3) gemm_exp_kernel(
        const char* __restrict__ A,   // img fp8, x4*scale
        const char* __restrict__ B,   // txt fp8, x64
        float* __restrict__ row_sum,
        float* __restrict__ col_sum,
        float* __restrict__ dsum,     // sum of true diag logits
        int*   __restrict__ counter,
        float* __restrict__ out) {
    __shared__ __align__(16) char As[128 * 128];
    __shared__ __align__(16) char Bs[128 * 128];

    const int tid  = threadIdx.x;
    const int lane = tid & 63;
    const int w    = tid >> 6;      // wave 0..3
    const int wr   = w >> 1;
    const int wc   = w & 1;
    const int ti   = blockIdx.y * 128;
    const int tj   = blockIdx.x * 128;

    const int quad = lane >> 4;
    const int l15  = lane & 15;

    // staging: GLD16 writes lane-ordered 16B slots; choose the global 16B
    // chunk so LDS holds 32B-chunks XOR-swizzled by (row&3), halves adjacent.
    const int s8  = lane & 7;                 // slot within row
    const int rq  = (lane >> 3) & 3;          // row & 3
    const int sg  = ((((s8 >> 1) ^ rq) << 1) | (s8 & 1));  // global 16B chunk
    const int sr  = lane >> 3;                // row within 8-row group

    f32x4 acc[4][4];
#pragma unroll
    for (int i = 0; i < 4; i++)
#pragma unroll
        for (int j = 0; j < 4; j++) acc[i][j] = (f32x4){0.f, 0.f, 0.f, 0.f};

    const int arow = wr * 64 + l15;
    const int brow = wc * 64 + l15;
    // fragment LDS offsets: row*128 + ((quad ^ (row&3)) << 5), row&3 = l15&3
    const int aoff = arow * 128 + ((quad ^ (l15 & 3)) << 5);
    const int boff = brow * 128 + ((quad ^ (l15 & 3)) << 5);

    for (int k0 = 0; k0 < D_DIM; k0 += 128) {
#pragma unroll
        for (int c = 0; c < 4; c++) {
            const int ch = w * 4 + c;             // wave-uniform
            const int r  = ch * 8 + sr;           // tile row 0..127
            GLD16(A + (size_t)(ti + r) * D_DIM + k0 + sg * 16, As + ch * 1024);
            GLD16(B + (size_t)(tj + r) * D_DIM + k0 + sg * 16, Bs + ch * 1024);
        }
        __syncthreads();

        i32x8 bfb[4];
#pragma unroll
        for (int fc = 0; fc < 4; fc++)
            bfb[fc] = *(const i32x8*)(Bs + boff + fc * (16 * 128));
#pragma unroll
        for (int fr = 0; fr < 4; fr++) {
            const i32x8 af = *(const i32x8*)(As + aoff + fr * (16 * 128));
#pragma unroll
            for (int fc = 0; fc < 4; fc++)
                acc[fr][fc] = __builtin_amdgcn_mfma_scale_f32_16x16x128_f8f6f4(
                    af, bfb[fc], acc[fr][fc], 0, 0, 0, 127, 0, 127);
        }
        __syncthreads();
    }

    // ---- diag: acc = 256 * logit ----
    if (blockIdx.x == blockIdx.y && wr == wc) {
        float dloc = 0.f;
#pragma unroll
        for (int fr = 0; fr < 4; fr++)
#pragma unroll
            for (int r = 0; r < 4; r++)
                if (l15 == quad * 4 + r) dloc += acc[fr][fr][r];
#pragma unroll
        for (int m = 1; m < 64; m <<= 1) dloc += __shfl_xor(dloc, m);
        if (lane == 0) atomicAdd(dsum, dloc * (1.0f / 256.0f));
    }

    // ---- exp: exp(logit) = exp2(acc * log2e/256) ----
    const float C_EXP = 1.44269504088896340736f / 256.0f;
#pragma unroll
    for (int fr = 0; fr < 4; fr++)
#pragma unroll
        for (int fc = 0; fc < 4; fc++)
#pragma unroll
            for (int r = 0; r < 4; r++)
                acc[fr][fc][r] = __builtin_amdgcn_exp2f(acc[fr][fc][r] * C_EXP);

    // row sums: elem (fr,fc,r) = exp(l[ti+wr*64+fr*16+quad*4+r][tj+wc*64+fc*16+l15])
    const int rowbase = ti + wr * 64;
#pragma unroll
    for (int fr = 0; fr < 4; fr++) {
#pragma unroll
        for (int r = 0; r < 4; r++) {
            float s = acc[fr][0][r] + acc[fr][1][r] + acc[fr][2][r] + acc[fr][3][r];
            s += __shfl_xor(s, 1);
            s += __shfl_xor(s, 2);
            s += __shfl_xor(s, 4);
            s += __shfl_xor(s, 8);
            if (l15 == 0)
                atomicAdd(&row_sum[rowbase + fr * 16 + quad * 4 + r], s);
        }
    }

    // col sums
    const int colbase = tj + wc * 64;
#pragma unroll
    for (int fc = 0; fc < 4; fc++) {
        float s = 0.f;
#pragma unroll
        for (int fr = 0; fr < 4; fr++)
#pragma unroll
            for (int r = 0; r < 4; r++) s += acc[fr][fc][r];
        s += __shfl_xor(s, 16);
        s += __shfl_xor(s, 32);
        if (quad == 0)
            atomicAdd(&col_sum[colbase + fc * 16 + l15], s);
    }

    // ---- last-block finish ----
    // Workgroup release = s_waitcnt vmcnt(0) only (no L2 maintenance — R3
    // lesson); device-scope atomics carry the data to the coherence point.
    __builtin_amdgcn_fence(__ATOMIC_RELEASE, "workgroup");
    int*   sh_flag = (int*)Bs;    // LDS reuse
    float* sh_sum  = (float*)As;
    if (tid == 0) sh_flag[0] = (atomicAdd(counter, 1) == (64 * 64 - 1)) ? 1 : 0;
    __syncthreads();
    if (sh_flag[0]) {
        // ONE agent-scope acquire in a single block: plain coalesced loads
        // below then see all device-scope atomic results.
        __builtin_amdgcn_fence(__ATOMIC_ACQUIRE, "agent");
        float s = 0.f;
        for (int i = tid * 4; i < N_ROWS; i += 1024) {   // 8 iters, float4 loads
            float4 r = *(const float4*)(row_sum + i);
            float4 c = *(const float4*)(col_sum + i);
            s += __logf(r.x * r.y * r.z * r.w) + __logf(c.x * c.y * c.z * c.w);
        }
#pragma unroll
        for (int m = 1; m < 64; m <<= 1) s += __shfl_xor(s, m);
        if (lane == 0) sh_sum[w] = s;
        __syncthreads();
        if (tid == 0) {
            float t = sh_sum[0] + sh_sum[1] + sh_sum[2] + sh_sum[3];
            out[0] = (t - 2.0f * dsum[0]) * (0.5f / (float)N_ROWS);
        }
    }
}

extern "C" void kernel_launch(void* const* d_in, const int* in_sizes, int n_in,
                              void* d_out, int out_size, void* d_ws, size_t ws_size,
                              hipStream_t stream) {
    const float* img     = (const float*)d_in[0];
    const float* txt     = (const float*)d_in[1];
    const float* scale_p = (const float*)d_in[2];
    float* out = (float*)d_out;

    char* ws = (char*)d_ws;
    char*  imgq    = ws;                                          // 8 MB
    char*  txtq    = ws + (size_t)8 * 1024 * 1024;                // 8 MB
    float* row_sum = (float*)(ws + (size_t)16 * 1024 * 1024);     // 32 KB
    float* col_sum = row_sum + N_ROWS;                            // 32 KB
    float* dsum    = row_sum + 2 * N_ROWS;
    int*   counter = (int*)(row_sum + 2 * N_ROWS) + 1;

    convert_zero_kernel<<<4096 + 64, 256, 0, stream>>>(img, txt, scale_p,
                                                       imgq, txtq, row_sum);

    dim3 grid(N_ROWS / 128, N_ROWS / 128);
    gemm_exp_kernel<<<grid, 256, 0, stream>>>(imgq, txtq, row_sum, col_sum,
                                              dsum, counter, out);
}